// Round 5
// baseline (2645.818 us; speedup 1.0000x reference)
//
#include <hip/hip_runtime.h>

// ---------------------------------------------------------------------------
// HeteroSAGE: CSR pull with src-windowed gathers (L2-resident h windows).
//   hist -> scan -> windowed fill -> proj (h bf16) ->
//   pull kernels: fused root matvec + 7-pass src-windowed mean + relu +
//   layer-2 dots -> pull2 scalar layer-2 (no atomics).
// ---------------------------------------------------------------------------

typedef unsigned short ushort_t;

#define WBITS 15   // 32768-node src windows -> 2MB bf16x32 rows, L2-resident

__device__ inline ushort_t f2bf(float f) {
    unsigned u = __float_as_uint(f);
    unsigned r = (u + 0x7FFFu + ((u >> 16) & 1u)) >> 16;
    return (ushort_t)r;
}
__device__ inline float bf2f_lo(unsigned u) { return __uint_as_float(u << 16); }
__device__ inline float bf2f_hi(unsigned u) { return __uint_as_float(u & 0xFFFF0000u); }

__global__ void prep_weights(
    const float* __restrict__ Wl1_pp, const float* __restrict__ Wr1_pp,
    const float* __restrict__ Wl1_ap, const float* __restrict__ Wr1_ap,
    const float* __restrict__ Wl1_pa, const float* __restrict__ Wr1_pa,
    const float* __restrict__ bl1_pp, const float* __restrict__ bl1_ap,
    const float* __restrict__ bl1_pa,
    const float* __restrict__ Wl2_pp, const float* __restrict__ bl2_pp,
    const float* __restrict__ Wr2_pp,
    const float* __restrict__ Wl2_ap, const float* __restrict__ bl2_ap,
    const float* __restrict__ Wr2_ap,
    const float* __restrict__ W_lin, const float* __restrict__ b_lin,
    float* __restrict__ Wn_p,   // 64 x 64: [Wl1_pp | Wl1_pa]
    float* __restrict__ Wn_a,   // 64 x 32: [Wl1_ap]
    float* __restrict__ Wr_p,   // 64 x 32: Wr1_pp + Wr1_ap
    float* __restrict__ Wr_a,   // 64 x 32: Wr1_pa
    float* __restrict__ bias_p, // 32
    float* __restrict__ bias_a, // 32
    float* __restrict__ vv)     // [0:32) v_pp  [32:64) v_r  [64] c2  [96:128) v_ap
{
    int t = threadIdx.x;
    for (int idx = t; idx < 64 * 64; idx += 256) {
        int i = idx / 64, j = idx % 64;
        Wn_p[idx] = (j < 32) ? Wl1_pp[i * 32 + j] : Wl1_pa[i * 32 + (j - 32)];
    }
    for (int idx = t; idx < 64 * 32; idx += 256) {
        Wn_a[idx] = Wl1_ap[idx];
        Wr_p[idx] = Wr1_pp[idx] + Wr1_ap[idx];
        Wr_a[idx] = Wr1_pa[idx];
    }
    if (t < 32) {
        bias_p[t] = bl1_pp[t] + bl1_ap[t];
        bias_a[t] = bl1_pa[t];
        float vpp = 0.f, vr = 0.f, vap = 0.f;
        for (int j = 0; j < 32; ++j) {
            float wl = W_lin[j];
            vpp += Wl2_pp[t * 32 + j] * wl;
            vr  += (Wr2_pp[t * 32 + j] + Wr2_ap[t * 32 + j]) * wl;
            vap += Wl2_ap[t * 32 + j] * wl;
        }
        vv[t] = vpp; vv[32 + t] = vr; vv[96 + t] = vap;
    }
    if (t == 0) {
        float c = b_lin[0];
        for (int j = 0; j < 32; ++j) c += (bl2_pp[j] + bl2_ap[j]) * W_lin[j];
        vv[64] = c;
    }
}

__global__ void hist_k(const int* __restrict__ dst, int* __restrict__ cnt, int E) {
    int e = blockIdx.x * blockDim.x + threadIdx.x;
    if (e < E) atomicAdd(&cnt[dst[e]], 1);
}

// chunked exclusive scan; writes row-start rs[] and working-cursor rn[] (= rs).
__global__ void scan_k(const int* __restrict__ cnt, int* __restrict__ rs,
                       int* __restrict__ rn, int* __restrict__ total, int N)
{
    __shared__ int wsum[4];
    __shared__ int bbase;
    int base = blockIdx.x * 2048 + threadIdx.x * 8;
    int v[8]; int ts = 0;
#pragma unroll
    for (int k = 0; k < 8; ++k) {
        int idx = base + k;
        v[k] = (idx < N) ? cnt[idx] : 0;
        ts += v[k];
    }
    int lane = threadIdx.x & 63;
    int incl = ts;
#pragma unroll
    for (int off = 1; off < 64; off <<= 1) {
        int o = __shfl_up(incl, off);
        if (lane >= off) incl += o;
    }
    int wid = threadIdx.x >> 6;
    if (lane == 63) wsum[wid] = incl;
    __syncthreads();
    int btot = wsum[0] + wsum[1] + wsum[2] + wsum[3];
    if (threadIdx.x == 0) bbase = atomicAdd(total, btot);
    int woff = 0;
    for (int w = 0; w < 4; ++w) if (w < wid) woff += wsum[w];
    __syncthreads();
    int run = bbase + woff + (incl - ts);
#pragma unroll
    for (int k = 0; k < 8; ++k) {
        int idx = base + k;
        if (idx < N) { rs[idx] = run; rn[idx] = run; }
        run += v[k];
    }
}

// windowed fill: pass p fills only dst in [p*32768,(p+1)*32768) so the active
// csr region (~2MB) is L2-resident; csr lines fill before eviction.
__global__ void fill_w(const int* __restrict__ src, const int* __restrict__ dst,
                       int* __restrict__ rn, int* __restrict__ csr, int E, int npass)
{
    int stride = gridDim.x * blockDim.x;
    int t0 = blockIdx.x * blockDim.x + threadIdx.x;
    for (int pass = 0; pass < npass; ++pass) {
        for (int e = t0; e < E; e += stride) {
            int d = dst[e];
            if ((d >> WBITS) == pass) {
                int pos = atomicAdd(&rn[d], 1);
                csr[pos] = src[e];
            }
        }
    }
}

__global__ void proj_paper(const float* __restrict__ x, const float* __restrict__ Wn,
                           ushort_t* __restrict__ h_pp, ushort_t* __restrict__ h_pa, int N)
{
    __shared__ float Wlds[64 * 64];
    for (int i = threadIdx.x; i < 64 * 64; i += 256) Wlds[i] = Wn[i];
    __syncthreads();
    int n = blockIdx.x * 8 + (threadIdx.x >> 5);
    int c = threadIdx.x & 31;
    if (n < N) {
        const float* xr = x + (size_t)n * 64;
        float a0 = 0.f, a1 = 0.f;
#pragma unroll
        for (int i = 0; i < 64; ++i) {
            float xv = xr[i];
            a0 += xv * Wlds[i * 64 + c];
            a1 += xv * Wlds[i * 64 + 32 + c];
        }
        h_pp[(size_t)n * 32 + c] = f2bf(a0);
        h_pa[(size_t)n * 32 + c] = f2bf(a1);
    }
}

__global__ void proj_author(const float* __restrict__ x, const float* __restrict__ Wn,
                            ushort_t* __restrict__ h_ap, int N)
{
    __shared__ float Wlds[64 * 32];
    for (int i = threadIdx.x; i < 64 * 32; i += 256) Wlds[i] = Wn[i];
    __syncthreads();
    int n = blockIdx.x * 8 + (threadIdx.x >> 5);
    int c = threadIdx.x & 31;
    if (n < N) {
        const float* xr = x + (size_t)n * 64;
        float a0 = 0.f;
#pragma unroll
        for (int i = 0; i < 64; ++i) a0 += xr[i] * Wlds[i * 32 + c];
        h_ap[(size_t)n * 32 + c] = f2bf(a0);
    }
}

// 16 lanes/node, 2 cols/lane. Fused root matvec (x,W in LDS) + src-windowed
// CSR gathers (register accumulators persist across passes) + mean + relu +
// layer-2 dots. Writes s_pp and out base term.
__global__ void pull_paper(const float* __restrict__ x,
                           const ushort_t* __restrict__ h_pp, const ushort_t* __restrict__ h_ap,
                           const int* __restrict__ csr_pp, const int* __restrict__ rs_pp,
                           const int* __restrict__ rn_pp,
                           const int* __restrict__ csr_ap, const int* __restrict__ rs_ap,
                           const int* __restrict__ rn_ap,
                           const float* __restrict__ Wr, const float* __restrict__ bias,
                           const float* __restrict__ vv,
                           float* __restrict__ s_pp, float* __restrict__ out, int N,
                           int npass_pp, int npass_ap)
{
    __shared__ float Wlds[64 * 32];
    __shared__ float xlds[16 * 65];
    __shared__ float v0[32], v1[32], blds[32];
    __shared__ float c2s;
    for (int i = threadIdx.x; i < 64 * 32; i += 256) Wlds[i] = Wr[i];
    if (threadIdx.x < 32) {
        v0[threadIdx.x] = vv[threadIdx.x];
        v1[threadIdx.x] = vv[32 + threadIdx.x];
        blds[threadIdx.x] = bias[threadIdx.x];
    }
    if (threadIdx.x == 0) c2s = vv[64];
    int base = blockIdx.x * 16;
    {
        int t4 = threadIdx.x * 4;
        int row = t4 >> 6, col = t4 & 63;
        int nn = base + row;
        float4 xv = (nn < N) ? *(const float4*)(x + (size_t)nn * 64 + col)
                             : make_float4(0.f, 0.f, 0.f, 0.f);
        float* dstp = &xlds[row * 65 + col];
        dstp[0] = xv.x; dstp[1] = xv.y; dstp[2] = xv.z; dstp[3] = xv.w;
    }
    __syncthreads();
    int g = threadIdx.x >> 4, c = threadIdx.x & 15;
    int n = base + g;
    if (n >= N) return;
    float r0 = blds[2 * c], r1 = blds[2 * c + 1];
#pragma unroll
    for (int i = 0; i < 64; ++i) {
        float xv = xlds[g * 65 + i];
        r0 += xv * Wlds[i * 32 + 2 * c];
        r1 += xv * Wlds[i * 32 + 2 * c + 1];
    }
    const ushort_t* hpp_c = h_pp + 2 * c;
    const ushort_t* hap_c = h_ap + 2 * c;
    // pp row, src-windowed
    int s1 = rs_pp[n], e1 = rn_pp[n];
    float a0 = 0.f, a1 = 0.f;
    for (int pass = 0; pass < npass_pp; ++pass) {
        for (int j = s1; j < e1; ++j) {
            int s = csr_pp[j];
            if ((s >> WBITS) == pass) {
                unsigned u = *(const unsigned*)(hpp_c + (size_t)s * 32);
                a0 += bf2f_lo(u); a1 += bf2f_hi(u);
            }
        }
    }
    // ap row, src-windowed
    int s2 = rs_ap[n], e2 = rn_ap[n];
    float b0 = 0.f, b1 = 0.f;
    for (int pass = 0; pass < npass_ap; ++pass) {
        for (int j = s2; j < e2; ++j) {
            int s = csr_ap[j];
            if ((s >> WBITS) == pass) {
                unsigned u = *(const unsigned*)(hap_c + (size_t)s * 32);
                b0 += bf2f_lo(u); b1 += bf2f_hi(u);
            }
        }
    }
    float ipp = 1.0f / fmaxf((float)(e1 - s1), 1.0f);
    float iap = 1.0f / fmaxf((float)(e2 - s2), 1.0f);
    float p0 = fmaxf(r0 + a0 * ipp + b0 * iap, 0.f);
    float p1 = fmaxf(r1 + a1 * ipp + b1 * iap, 0.f);
    float d0 = p0 * v0[2 * c] + p1 * v0[2 * c + 1];
    float d1 = p0 * v1[2 * c] + p1 * v1[2 * c + 1];
#pragma unroll
    for (int off = 1; off < 16; off <<= 1) {
        d0 += __shfl_xor(d0, off);
        d1 += __shfl_xor(d1, off);
    }
    if (c == 0) { s_pp[n] = d0; out[n] = d1 + c2s; }
}

__global__ void pull_author(const float* __restrict__ x, const ushort_t* __restrict__ h_pa,
                            const int* __restrict__ csr_pa, const int* __restrict__ rs_pa,
                            const int* __restrict__ rn_pa,
                            const float* __restrict__ Wr, const float* __restrict__ bias,
                            const float* __restrict__ vv, float* __restrict__ s_ap, int N,
                            int npass)
{
    __shared__ float Wlds[64 * 32];
    __shared__ float xlds[16 * 65];
    __shared__ float v0[32], blds[32];
    for (int i = threadIdx.x; i < 64 * 32; i += 256) Wlds[i] = Wr[i];
    if (threadIdx.x < 32) {
        v0[threadIdx.x] = vv[96 + threadIdx.x];
        blds[threadIdx.x] = bias[threadIdx.x];
    }
    int base = blockIdx.x * 16;
    {
        int t4 = threadIdx.x * 4;
        int row = t4 >> 6, col = t4 & 63;
        int nn = base + row;
        float4 xv = (nn < N) ? *(const float4*)(x + (size_t)nn * 64 + col)
                             : make_float4(0.f, 0.f, 0.f, 0.f);
        float* dstp = &xlds[row * 65 + col];
        dstp[0] = xv.x; dstp[1] = xv.y; dstp[2] = xv.z; dstp[3] = xv.w;
    }
    __syncthreads();
    int g = threadIdx.x >> 4, c = threadIdx.x & 15;
    int n = base + g;
    if (n >= N) return;
    float r0 = blds[2 * c], r1 = blds[2 * c + 1];
#pragma unroll
    for (int i = 0; i < 64; ++i) {
        float xv = xlds[g * 65 + i];
        r0 += xv * Wlds[i * 32 + 2 * c];
        r1 += xv * Wlds[i * 32 + 2 * c + 1];
    }
    const ushort_t* hpa_c = h_pa + 2 * c;
    int s1 = rs_pa[n], e1 = rn_pa[n];
    float a0 = 0.f, a1 = 0.f;
    for (int pass = 0; pass < npass; ++pass) {
        for (int j = s1; j < e1; ++j) {
            int s = csr_pa[j];
            if ((s >> WBITS) == pass) {
                unsigned u = *(const unsigned*)(hpa_c + (size_t)s * 32);
                a0 += bf2f_lo(u); a1 += bf2f_hi(u);
            }
        }
    }
    float ip = 1.0f / fmaxf((float)(e1 - s1), 1.0f);
    float p0 = fmaxf(r0 + a0 * ip, 0.f);
    float p1 = fmaxf(r1 + a1 * ip, 0.f);
    float d0 = p0 * v0[2 * c] + p1 * v0[2 * c + 1];
#pragma unroll
    for (int off = 1; off < 16; off <<= 1) d0 += __shfl_xor(d0, off);
    if (c == 0) s_ap[n] = d0;
}

// layer-2 scalar pull, 4 lanes/node; s tables are L2-resident (0.8/0.4 MB).
__global__ void pull2(const float* __restrict__ s_pp, const float* __restrict__ s_ap,
                      const int* __restrict__ csr_pp, const int* __restrict__ rs_pp,
                      const int* __restrict__ rn_pp,
                      const int* __restrict__ csr_ap, const int* __restrict__ rs_ap,
                      const int* __restrict__ rn_ap,
                      float* __restrict__ out, int N)
{
    int g = (blockIdx.x * blockDim.x + threadIdx.x) >> 2;
    int c = threadIdx.x & 3;
    if (g >= N) return;
    int s1 = rs_pp[g], e1 = rn_pp[g];
    float t = 0.f;
    for (int j = s1 + c; j < e1; j += 4) t += s_pp[csr_pp[j]];
    int s2 = rs_ap[g], e2 = rn_ap[g];
    float u = 0.f;
    for (int j = s2 + c; j < e2; j += 4) u += s_ap[csr_ap[j]];
    t += __shfl_xor(t, 1); t += __shfl_xor(t, 2);
    u += __shfl_xor(u, 1); u += __shfl_xor(u, 2);
    if (c == 0) {
        out[g] += t / fmaxf((float)(e1 - s1), 1.f) + u / fmaxf((float)(e2 - s2), 1.f);
    }
}

extern "C" void kernel_launch(void* const* d_in, const int* in_sizes, int n_in,
                              void* d_out, int out_size, void* d_ws, size_t ws_size,
                              hipStream_t stream)
{
    const float* x_paper  = (const float*)d_in[0];
    const float* x_author = (const float*)d_in[1];
    const int* src_pp = (const int*)d_in[2];
    const int* dst_pp = (const int*)d_in[3];
    const int* src_ap = (const int*)d_in[4];
    const int* dst_ap = (const int*)d_in[5];
    const int* src_pa = (const int*)d_in[6];
    const int* dst_pa = (const int*)d_in[7];
    const float* Wl1_pp = (const float*)d_in[8];
    const float* bl1_pp = (const float*)d_in[9];
    const float* Wr1_pp = (const float*)d_in[10];
    const float* Wl1_ap = (const float*)d_in[11];
    const float* bl1_ap = (const float*)d_in[12];
    const float* Wr1_ap = (const float*)d_in[13];
    const float* Wl1_pa = (const float*)d_in[14];
    const float* bl1_pa = (const float*)d_in[15];
    const float* Wr1_pa = (const float*)d_in[16];
    const float* Wl2_pp = (const float*)d_in[17];
    const float* bl2_pp = (const float*)d_in[18];
    const float* Wr2_pp = (const float*)d_in[19];
    const float* Wl2_ap = (const float*)d_in[20];
    const float* bl2_ap = (const float*)d_in[21];
    const float* Wr2_ap = (const float*)d_in[22];
    const float* W_lin  = (const float*)d_in[23];
    const float* b_lin  = (const float*)d_in[24];

    const int NP = in_sizes[0] / 64;
    const int NA = in_sizes[1] / 64;
    const int E_PP = in_sizes[2];
    const int E_AP = in_sizes[4];
    const int E_PA = in_sizes[6];

    // ---- workspace ----
    char* wp = (char*)d_ws;
    int* cnt_pp = (int*)wp;         wp += (size_t)NP * 4;
    int* cnt_ap = (int*)wp;         wp += (size_t)NP * 4;
    int* cnt_pa = (int*)wp;         wp += (size_t)NA * 4;
    int* totals = (int*)wp;         wp += 4 * 4;
    int* rs_pp  = (int*)wp;         wp += (size_t)NP * 4;
    int* rs_ap  = (int*)wp;         wp += (size_t)NP * 4;
    int* rs_pa  = (int*)wp;         wp += (size_t)NA * 4;
    int* rn_pp  = (int*)wp;         wp += (size_t)NP * 4;
    int* rn_ap  = (int*)wp;         wp += (size_t)NP * 4;
    int* rn_pa  = (int*)wp;         wp += (size_t)NA * 4;
    int* csr_pp = (int*)wp;         wp += (size_t)E_PP * 4;
    int* csr_ap = (int*)wp;         wp += (size_t)E_AP * 4;
    int* csr_pa = (int*)wp;         wp += (size_t)E_PA * 4;
    ushort_t* h_pp = (ushort_t*)wp; wp += (size_t)NP * 32 * 2;
    ushort_t* h_pa = (ushort_t*)wp; wp += (size_t)NP * 32 * 2;
    ushort_t* h_ap = (ushort_t*)wp; wp += (size_t)NA * 32 * 2;
    float* s_pp   = (float*)wp;     wp += (size_t)NP * 4;
    float* s_ap   = (float*)wp;     wp += (size_t)NA * 4;
    float* Wn_p   = (float*)wp;     wp += 64 * 64 * 4;
    float* Wn_a   = (float*)wp;     wp += 64 * 32 * 4;
    float* Wr_p   = (float*)wp;     wp += 64 * 32 * 4;
    float* Wr_a   = (float*)wp;     wp += 64 * 32 * 4;
    float* bias_p = (float*)wp;     wp += 32 * 4;
    float* bias_a = (float*)wp;     wp += 32 * 4;
    float* vv     = (float*)wp;     wp += 128 * 4;

    float* out = (float*)d_out;

    const int np_pass = (NP + (1 << WBITS) - 1) >> WBITS;   // 7
    const int na_pass = (NA + (1 << WBITS) - 1) >> WBITS;   // 4

    // zero counts + totals (contiguous at ws start)
    hipMemsetAsync(d_ws, 0, ((size_t)(2 * NP + NA) + 4) * sizeof(int), stream);

    prep_weights<<<1, 256, 0, stream>>>(
        Wl1_pp, Wr1_pp, Wl1_ap, Wr1_ap, Wl1_pa, Wr1_pa,
        bl1_pp, bl1_ap, bl1_pa,
        Wl2_pp, bl2_pp, Wr2_pp, Wl2_ap, bl2_ap, Wr2_ap,
        W_lin, b_lin, Wn_p, Wn_a, Wr_p, Wr_a, bias_p, bias_a, vv);

    hist_k<<<(E_PP + 255) / 256, 256, 0, stream>>>(dst_pp, cnt_pp, E_PP);
    hist_k<<<(E_AP + 255) / 256, 256, 0, stream>>>(dst_ap, cnt_ap, E_AP);
    hist_k<<<(E_PA + 255) / 256, 256, 0, stream>>>(dst_pa, cnt_pa, E_PA);

    scan_k<<<(NP + 2047) / 2048, 256, 0, stream>>>(cnt_pp, rs_pp, rn_pp, totals + 0, NP);
    scan_k<<<(NP + 2047) / 2048, 256, 0, stream>>>(cnt_ap, rs_ap, rn_ap, totals + 1, NP);
    scan_k<<<(NA + 2047) / 2048, 256, 0, stream>>>(cnt_pa, rs_pa, rn_pa, totals + 2, NA);

    fill_w<<<2048, 256, 0, stream>>>(src_pp, dst_pp, rn_pp, csr_pp, E_PP, np_pass);
    fill_w<<<2048, 256, 0, stream>>>(src_ap, dst_ap, rn_ap, csr_ap, E_AP, np_pass);
    fill_w<<<2048, 256, 0, stream>>>(src_pa, dst_pa, rn_pa, csr_pa, E_PA, na_pass);

    proj_paper<<<(NP + 7) / 8, 256, 0, stream>>>(x_paper, Wn_p, h_pp, h_pa, NP);
    proj_author<<<(NA + 7) / 8, 256, 0, stream>>>(x_author, Wn_a, h_ap, NA);

    pull_paper<<<(NP + 15) / 16, 256, 0, stream>>>(
        x_paper, h_pp, h_ap, csr_pp, rs_pp, rn_pp, csr_ap, rs_ap, rn_ap,
        Wr_p, bias_p, vv, s_pp, out, NP, np_pass, na_pass);
    pull_author<<<(NA + 15) / 16, 256, 0, stream>>>(
        x_author, h_pa, csr_pa, rs_pa, rn_pa, Wr_a, bias_a, vv, s_ap, NA, np_pass);

    pull2<<<((size_t)NP * 4 + 255) / 256, 256, 0, stream>>>(
        s_pp, s_ap, csr_pp, rs_pp, rn_pp, csr_ap, rs_ap, rn_ap, out, NP);
}

// Round 6
// 964.539 us; speedup vs baseline: 2.7431x; 2.7431x over previous
//
#include <hip/hip_runtime.h>

// ---------------------------------------------------------------------------
// HeteroSAGE: CSR pull, high-occupancy pull kernels (root precomputed).
//   hist -> scan -> windowed fill -> proj (h bf16 + root f32) ->
//   pull (tiny LDS, unroll-4 gathers, launch_bounds 8 waves/EU) ->
//   pull2 scalar layer-2 (no atomics).
// ---------------------------------------------------------------------------

typedef unsigned short ushort_t;

#define WBITS 15   // 32768-dst windows for the CSR fill (csr window ~2MB, L2-resident)

__device__ inline ushort_t f2bf(float f) {
    unsigned u = __float_as_uint(f);
    unsigned r = (u + 0x7FFFu + ((u >> 16) & 1u)) >> 16;
    return (ushort_t)r;
}
__device__ inline float bf2f_lo(unsigned u) { return __uint_as_float(u << 16); }
__device__ inline float bf2f_hi(unsigned u) { return __uint_as_float(u & 0xFFFF0000u); }

__global__ void prep_weights(
    const float* __restrict__ Wl1_pp, const float* __restrict__ Wr1_pp,
    const float* __restrict__ Wl1_ap, const float* __restrict__ Wr1_ap,
    const float* __restrict__ Wl1_pa, const float* __restrict__ Wr1_pa,
    const float* __restrict__ bl1_pp, const float* __restrict__ bl1_ap,
    const float* __restrict__ bl1_pa,
    const float* __restrict__ Wl2_pp, const float* __restrict__ bl2_pp,
    const float* __restrict__ Wr2_pp,
    const float* __restrict__ Wl2_ap, const float* __restrict__ bl2_ap,
    const float* __restrict__ Wr2_ap,
    const float* __restrict__ W_lin, const float* __restrict__ b_lin,
    float* __restrict__ Wcomb_p,  // 64 x 96: [Wl1_pp | Wl1_pa | Wr1_pp+Wr1_ap]
    float* __restrict__ Wcomb_a,  // 64 x 64: [Wl1_ap | Wr1_pa]
    float* __restrict__ bias_p,   // 32
    float* __restrict__ bias_a,   // 32
    float* __restrict__ vv)       // [0:32) v_pp  [32:64) v_r  [64] c2  [96:128) v_ap
{
    int t = threadIdx.x;
    for (int idx = t; idx < 64 * 96; idx += 256) {
        int i = idx / 96, j = idx % 96;
        float v;
        if (j < 32)       v = Wl1_pp[i * 32 + j];
        else if (j < 64)  v = Wl1_pa[i * 32 + (j - 32)];
        else              v = Wr1_pp[i * 32 + (j - 64)] + Wr1_ap[i * 32 + (j - 64)];
        Wcomb_p[idx] = v;
    }
    for (int idx = t; idx < 64 * 64; idx += 256) {
        int i = idx / 64, j = idx % 64;
        Wcomb_a[idx] = (j < 32) ? Wl1_ap[i * 32 + j] : Wr1_pa[i * 32 + (j - 32)];
    }
    if (t < 32) {
        bias_p[t] = bl1_pp[t] + bl1_ap[t];
        bias_a[t] = bl1_pa[t];
        float vpp = 0.f, vr = 0.f, vap = 0.f;
        for (int j = 0; j < 32; ++j) {
            float wl = W_lin[j];
            vpp += Wl2_pp[t * 32 + j] * wl;
            vr  += (Wr2_pp[t * 32 + j] + Wr2_ap[t * 32 + j]) * wl;
            vap += Wl2_ap[t * 32 + j] * wl;
        }
        vv[t] = vpp; vv[32 + t] = vr; vv[96 + t] = vap;
    }
    if (t == 0) {
        float c = b_lin[0];
        for (int j = 0; j < 32; ++j) c += (bl2_pp[j] + bl2_ap[j]) * W_lin[j];
        vv[64] = c;
    }
}

__global__ void hist_k(const int* __restrict__ dst, int* __restrict__ cnt, int E) {
    int e = blockIdx.x * blockDim.x + threadIdx.x;
    if (e < E) atomicAdd(&cnt[dst[e]], 1);
}

// chunked exclusive scan; writes row-start rs[] and working-cursor rn[] (= rs).
__global__ void scan_k(const int* __restrict__ cnt, int* __restrict__ rs,
                       int* __restrict__ rn, int* __restrict__ total, int N)
{
    __shared__ int wsum[4];
    __shared__ int bbase;
    int base = blockIdx.x * 2048 + threadIdx.x * 8;
    int v[8]; int ts = 0;
#pragma unroll
    for (int k = 0; k < 8; ++k) {
        int idx = base + k;
        v[k] = (idx < N) ? cnt[idx] : 0;
        ts += v[k];
    }
    int lane = threadIdx.x & 63;
    int incl = ts;
#pragma unroll
    for (int off = 1; off < 64; off <<= 1) {
        int o = __shfl_up(incl, off);
        if (lane >= off) incl += o;
    }
    int wid = threadIdx.x >> 6;
    if (lane == 63) wsum[wid] = incl;
    __syncthreads();
    int btot = wsum[0] + wsum[1] + wsum[2] + wsum[3];
    if (threadIdx.x == 0) bbase = atomicAdd(total, btot);
    int woff = 0;
    for (int w = 0; w < 4; ++w) if (w < wid) woff += wsum[w];
    __syncthreads();
    int run = bbase + woff + (incl - ts);
#pragma unroll
    for (int k = 0; k < 8; ++k) {
        int idx = base + k;
        if (idx < N) { rs[idx] = run; rn[idx] = run; }
        run += v[k];
    }
}

// windowed fill: pass p fills only dst in [p*32768,(p+1)*32768) so the active
// csr region (~2MB) is L2-resident; csr lines fill before eviction.
__global__ void fill_w(const int* __restrict__ src, const int* __restrict__ dst,
                       int* __restrict__ rn, int* __restrict__ csr, int E, int npass)
{
    int stride = gridDim.x * blockDim.x;
    int t0 = blockIdx.x * blockDim.x + threadIdx.x;
    for (int pass = 0; pass < npass; ++pass) {
        for (int e = t0; e < E; e += stride) {
            int d = dst[e];
            if ((d >> WBITS) == pass) {
                int pos = atomicAdd(&rn[d], 1);
                csr[pos] = src[e];
            }
        }
    }
}

// paper projection: h_pp, h_pa (bf16 neighbor features) + root_p (f32, incl bias)
__global__ void proj_paper(const float* __restrict__ x, const float* __restrict__ Wc,
                           const float* __restrict__ bias,
                           ushort_t* __restrict__ h_pp, ushort_t* __restrict__ h_pa,
                           float* __restrict__ root_p, int N)
{
    __shared__ float Wlds[64 * 96];
    __shared__ float blds[32];
    for (int i = threadIdx.x; i < 64 * 96; i += 256) Wlds[i] = Wc[i];
    if (threadIdx.x < 32) blds[threadIdx.x] = bias[threadIdx.x];
    __syncthreads();
    int n = blockIdx.x * 8 + (threadIdx.x >> 5);
    int c = threadIdx.x & 31;
    if (n < N) {
        const float* xr = x + (size_t)n * 64;
        float a0 = 0.f, a1 = 0.f, a2 = 0.f;
#pragma unroll
        for (int i = 0; i < 64; ++i) {
            float xv = xr[i];
            a0 += xv * Wlds[i * 96 + c];
            a1 += xv * Wlds[i * 96 + 32 + c];
            a2 += xv * Wlds[i * 96 + 64 + c];
        }
        h_pp[(size_t)n * 32 + c] = f2bf(a0);
        h_pa[(size_t)n * 32 + c] = f2bf(a1);
        root_p[(size_t)n * 32 + c] = a2 + blds[c];
    }
}

__global__ void proj_author(const float* __restrict__ x, const float* __restrict__ Wc,
                            const float* __restrict__ bias,
                            ushort_t* __restrict__ h_ap, float* __restrict__ root_a, int N)
{
    __shared__ float Wlds[64 * 64];
    __shared__ float blds[32];
    for (int i = threadIdx.x; i < 64 * 64; i += 256) Wlds[i] = Wc[i];
    if (threadIdx.x < 32) blds[threadIdx.x] = bias[threadIdx.x];
    __syncthreads();
    int n = blockIdx.x * 8 + (threadIdx.x >> 5);
    int c = threadIdx.x & 31;
    if (n < N) {
        const float* xr = x + (size_t)n * 64;
        float a0 = 0.f, a1 = 0.f;
#pragma unroll
        for (int i = 0; i < 64; ++i) {
            float xv = xr[i];
            a0 += xv * Wlds[i * 64 + c];
            a1 += xv * Wlds[i * 64 + 32 + c];
        }
        h_ap[(size_t)n * 32 + c] = f2bf(a0);
        root_a[(size_t)n * 32 + c] = a1 + blds[c];
    }
}

// 16 lanes/node, 2 cols/lane, tiny LDS, high occupancy. Unroll-4 independent
// gathers; fuses mean + root + relu + layer-2 dot products.
__global__ __launch_bounds__(256, 8)
void pull_paper(const ushort_t* __restrict__ h_pp, const ushort_t* __restrict__ h_ap,
                const float* __restrict__ root,
                const int* __restrict__ csr_pp, const int* __restrict__ rs_pp,
                const int* __restrict__ rn_pp,
                const int* __restrict__ csr_ap, const int* __restrict__ rs_ap,
                const int* __restrict__ rn_ap,
                const float* __restrict__ vv,
                float* __restrict__ s_pp, float* __restrict__ out, int N)
{
    __shared__ float v0[32], v1[32];
    __shared__ float c2s;
    if (threadIdx.x < 32) { v0[threadIdx.x] = vv[threadIdx.x]; v1[threadIdx.x] = vv[32 + threadIdx.x]; }
    if (threadIdx.x == 0) c2s = vv[64];
    __syncthreads();
    int n = blockIdx.x * 16 + (threadIdx.x >> 4);
    if (n >= N) return;
    int c = threadIdx.x & 15;
    const ushort_t* hpp_c = h_pp + 2 * c;
    const ushort_t* hap_c = h_ap + 2 * c;
    // pp row
    int s1 = rs_pp[n], e1 = rn_pp[n];
    float a0 = 0.f, a1 = 0.f;
    int j = s1;
    for (; j + 4 <= e1; j += 4) {
        int i0 = csr_pp[j], i1 = csr_pp[j + 1], i2 = csr_pp[j + 2], i3 = csr_pp[j + 3];
        unsigned u0 = *(const unsigned*)(hpp_c + (size_t)i0 * 32);
        unsigned u1 = *(const unsigned*)(hpp_c + (size_t)i1 * 32);
        unsigned u2 = *(const unsigned*)(hpp_c + (size_t)i2 * 32);
        unsigned u3 = *(const unsigned*)(hpp_c + (size_t)i3 * 32);
        a0 += (bf2f_lo(u0) + bf2f_lo(u1)) + (bf2f_lo(u2) + bf2f_lo(u3));
        a1 += (bf2f_hi(u0) + bf2f_hi(u1)) + (bf2f_hi(u2) + bf2f_hi(u3));
    }
    for (; j < e1; ++j) {
        unsigned u0 = *(const unsigned*)(hpp_c + (size_t)csr_pp[j] * 32);
        a0 += bf2f_lo(u0); a1 += bf2f_hi(u0);
    }
    // ap row
    int s2 = rs_ap[n], e2 = rn_ap[n];
    float b0 = 0.f, b1 = 0.f;
    j = s2;
    for (; j + 4 <= e2; j += 4) {
        int i0 = csr_ap[j], i1 = csr_ap[j + 1], i2 = csr_ap[j + 2], i3 = csr_ap[j + 3];
        unsigned u0 = *(const unsigned*)(hap_c + (size_t)i0 * 32);
        unsigned u1 = *(const unsigned*)(hap_c + (size_t)i1 * 32);
        unsigned u2 = *(const unsigned*)(hap_c + (size_t)i2 * 32);
        unsigned u3 = *(const unsigned*)(hap_c + (size_t)i3 * 32);
        b0 += (bf2f_lo(u0) + bf2f_lo(u1)) + (bf2f_lo(u2) + bf2f_lo(u3));
        b1 += (bf2f_hi(u0) + bf2f_hi(u1)) + (bf2f_hi(u2) + bf2f_hi(u3));
    }
    for (; j < e2; ++j) {
        unsigned u0 = *(const unsigned*)(hap_c + (size_t)csr_ap[j] * 32);
        b0 += bf2f_lo(u0); b1 += bf2f_hi(u0);
    }
    float ipp = 1.0f / fmaxf((float)(e1 - s1), 1.0f);
    float iap = 1.0f / fmaxf((float)(e2 - s2), 1.0f);
    float p0 = fmaxf(root[(size_t)n * 32 + 2 * c]     + a0 * ipp + b0 * iap, 0.f);
    float p1 = fmaxf(root[(size_t)n * 32 + 2 * c + 1] + a1 * ipp + b1 * iap, 0.f);
    float d0 = p0 * v0[2 * c] + p1 * v0[2 * c + 1];
    float d1 = p0 * v1[2 * c] + p1 * v1[2 * c + 1];
#pragma unroll
    for (int off = 1; off < 16; off <<= 1) {
        d0 += __shfl_xor(d0, off);
        d1 += __shfl_xor(d1, off);
    }
    if (c == 0) { s_pp[n] = d0; out[n] = d1 + c2s; }
}

__global__ __launch_bounds__(256, 8)
void pull_author(const ushort_t* __restrict__ h_pa, const float* __restrict__ root,
                 const int* __restrict__ csr_pa, const int* __restrict__ rs_pa,
                 const int* __restrict__ rn_pa,
                 const float* __restrict__ vv, float* __restrict__ s_ap, int N)
{
    __shared__ float v0[32];
    if (threadIdx.x < 32) v0[threadIdx.x] = vv[96 + threadIdx.x];
    __syncthreads();
    int n = blockIdx.x * 16 + (threadIdx.x >> 4);
    if (n >= N) return;
    int c = threadIdx.x & 15;
    const ushort_t* hpa_c = h_pa + 2 * c;
    int s1 = rs_pa[n], e1 = rn_pa[n];
    float a0 = 0.f, a1 = 0.f;
    int j = s1;
    for (; j + 4 <= e1; j += 4) {
        int i0 = csr_pa[j], i1 = csr_pa[j + 1], i2 = csr_pa[j + 2], i3 = csr_pa[j + 3];
        unsigned u0 = *(const unsigned*)(hpa_c + (size_t)i0 * 32);
        unsigned u1 = *(const unsigned*)(hpa_c + (size_t)i1 * 32);
        unsigned u2 = *(const unsigned*)(hpa_c + (size_t)i2 * 32);
        unsigned u3 = *(const unsigned*)(hpa_c + (size_t)i3 * 32);
        a0 += (bf2f_lo(u0) + bf2f_lo(u1)) + (bf2f_lo(u2) + bf2f_lo(u3));
        a1 += (bf2f_hi(u0) + bf2f_hi(u1)) + (bf2f_hi(u2) + bf2f_hi(u3));
    }
    for (; j < e1; ++j) {
        unsigned u0 = *(const unsigned*)(hpa_c + (size_t)csr_pa[j] * 32);
        a0 += bf2f_lo(u0); a1 += bf2f_hi(u0);
    }
    float ip = 1.0f / fmaxf((float)(e1 - s1), 1.0f);
    float p0 = fmaxf(root[(size_t)n * 32 + 2 * c]     + a0 * ip, 0.f);
    float p1 = fmaxf(root[(size_t)n * 32 + 2 * c + 1] + a1 * ip, 0.f);
    float d0 = p0 * v0[2 * c] + p1 * v0[2 * c + 1];
#pragma unroll
    for (int off = 1; off < 16; off <<= 1) d0 += __shfl_xor(d0, off);
    if (c == 0) s_ap[n] = d0;
}

// layer-2 scalar pull, 4 lanes/node; s tables are small (0.8/0.4 MB).
__global__ __launch_bounds__(256, 8)
void pull2(const float* __restrict__ s_pp, const float* __restrict__ s_ap,
           const int* __restrict__ csr_pp, const int* __restrict__ rs_pp,
           const int* __restrict__ rn_pp,
           const int* __restrict__ csr_ap, const int* __restrict__ rs_ap,
           const int* __restrict__ rn_ap,
           float* __restrict__ out, int N)
{
    int g = (blockIdx.x * blockDim.x + threadIdx.x) >> 2;
    int c = threadIdx.x & 3;
    if (g >= N) return;
    int s1 = rs_pp[g], e1 = rn_pp[g];
    float t = 0.f;
    for (int j = s1 + c; j < e1; j += 4) t += s_pp[csr_pp[j]];
    int s2 = rs_ap[g], e2 = rn_ap[g];
    float u = 0.f;
    for (int j = s2 + c; j < e2; j += 4) u += s_ap[csr_ap[j]];
    t += __shfl_xor(t, 1); t += __shfl_xor(t, 2);
    u += __shfl_xor(u, 1); u += __shfl_xor(u, 2);
    if (c == 0) {
        out[g] += t / fmaxf((float)(e1 - s1), 1.f) + u / fmaxf((float)(e2 - s2), 1.f);
    }
}

extern "C" void kernel_launch(void* const* d_in, const int* in_sizes, int n_in,
                              void* d_out, int out_size, void* d_ws, size_t ws_size,
                              hipStream_t stream)
{
    const float* x_paper  = (const float*)d_in[0];
    const float* x_author = (const float*)d_in[1];
    const int* src_pp = (const int*)d_in[2];
    const int* dst_pp = (const int*)d_in[3];
    const int* src_ap = (const int*)d_in[4];
    const int* dst_ap = (const int*)d_in[5];
    const int* src_pa = (const int*)d_in[6];
    const int* dst_pa = (const int*)d_in[7];
    const float* Wl1_pp = (const float*)d_in[8];
    const float* bl1_pp = (const float*)d_in[9];
    const float* Wr1_pp = (const float*)d_in[10];
    const float* Wl1_ap = (const float*)d_in[11];
    const float* bl1_ap = (const float*)d_in[12];
    const float* Wr1_ap = (const float*)d_in[13];
    const float* Wl1_pa = (const float*)d_in[14];
    const float* bl1_pa = (const float*)d_in[15];
    const float* Wr1_pa = (const float*)d_in[16];
    const float* Wl2_pp = (const float*)d_in[17];
    const float* bl2_pp = (const float*)d_in[18];
    const float* Wr2_pp = (const float*)d_in[19];
    const float* Wl2_ap = (const float*)d_in[20];
    const float* bl2_ap = (const float*)d_in[21];
    const float* Wr2_ap = (const float*)d_in[22];
    const float* W_lin  = (const float*)d_in[23];
    const float* b_lin  = (const float*)d_in[24];

    const int NP = in_sizes[0] / 64;
    const int NA = in_sizes[1] / 64;
    const int E_PP = in_sizes[2];
    const int E_AP = in_sizes[4];
    const int E_PA = in_sizes[6];

    // ---- workspace ----
    char* wp = (char*)d_ws;
    int* cnt_pp = (int*)wp;         wp += (size_t)NP * 4;
    int* cnt_ap = (int*)wp;         wp += (size_t)NP * 4;
    int* cnt_pa = (int*)wp;         wp += (size_t)NA * 4;
    int* totals = (int*)wp;         wp += 4 * 4;
    int* rs_pp  = (int*)wp;         wp += (size_t)NP * 4;
    int* rs_ap  = (int*)wp;         wp += (size_t)NP * 4;
    int* rs_pa  = (int*)wp;         wp += (size_t)NA * 4;
    int* rn_pp  = (int*)wp;         wp += (size_t)NP * 4;
    int* rn_ap  = (int*)wp;         wp += (size_t)NP * 4;
    int* rn_pa  = (int*)wp;         wp += (size_t)NA * 4;
    int* csr_pp = (int*)wp;         wp += (size_t)E_PP * 4;
    int* csr_ap = (int*)wp;         wp += (size_t)E_AP * 4;
    int* csr_pa = (int*)wp;         wp += (size_t)E_PA * 4;
    ushort_t* h_pp = (ushort_t*)wp; wp += (size_t)NP * 32 * 2;
    ushort_t* h_pa = (ushort_t*)wp; wp += (size_t)NP * 32 * 2;
    ushort_t* h_ap = (ushort_t*)wp; wp += (size_t)NA * 32 * 2;
    float* root_p = (float*)wp;     wp += (size_t)NP * 32 * 4;
    float* root_a = (float*)wp;     wp += (size_t)NA * 32 * 4;
    float* s_pp   = (float*)wp;     wp += (size_t)NP * 4;
    float* s_ap   = (float*)wp;     wp += (size_t)NA * 4;
    float* Wcomb_p = (float*)wp;    wp += 64 * 96 * 4;
    float* Wcomb_a = (float*)wp;    wp += 64 * 64 * 4;
    float* bias_p = (float*)wp;     wp += 32 * 4;
    float* bias_a = (float*)wp;     wp += 32 * 4;
    float* vv     = (float*)wp;     wp += 128 * 4;

    float* out = (float*)d_out;

    const int np_pass = (NP + (1 << WBITS) - 1) >> WBITS;   // 7
    const int na_pass = (NA + (1 << WBITS) - 1) >> WBITS;   // 4

    // zero counts + totals (contiguous at ws start)
    hipMemsetAsync(d_ws, 0, ((size_t)(2 * NP + NA) + 4) * sizeof(int), stream);

    prep_weights<<<1, 256, 0, stream>>>(
        Wl1_pp, Wr1_pp, Wl1_ap, Wr1_ap, Wl1_pa, Wr1_pa,
        bl1_pp, bl1_ap, bl1_pa,
        Wl2_pp, bl2_pp, Wr2_pp, Wl2_ap, bl2_ap, Wr2_ap,
        W_lin, b_lin, Wcomb_p, Wcomb_a, bias_p, bias_a, vv);

    hist_k<<<(E_PP + 255) / 256, 256, 0, stream>>>(dst_pp, cnt_pp, E_PP);
    hist_k<<<(E_AP + 255) / 256, 256, 0, stream>>>(dst_ap, cnt_ap, E_AP);
    hist_k<<<(E_PA + 255) / 256, 256, 0, stream>>>(dst_pa, cnt_pa, E_PA);

    scan_k<<<(NP + 2047) / 2048, 256, 0, stream>>>(cnt_pp, rs_pp, rn_pp, totals + 0, NP);
    scan_k<<<(NP + 2047) / 2048, 256, 0, stream>>>(cnt_ap, rs_ap, rn_ap, totals + 1, NP);
    scan_k<<<(NA + 2047) / 2048, 256, 0, stream>>>(cnt_pa, rs_pa, rn_pa, totals + 2, NA);

    fill_w<<<2048, 256, 0, stream>>>(src_pp, dst_pp, rn_pp, csr_pp, E_PP, np_pass);
    fill_w<<<2048, 256, 0, stream>>>(src_ap, dst_ap, rn_ap, csr_ap, E_AP, np_pass);
    fill_w<<<2048, 256, 0, stream>>>(src_pa, dst_pa, rn_pa, csr_pa, E_PA, na_pass);

    proj_paper<<<(NP + 7) / 8, 256, 0, stream>>>(x_paper, Wcomb_p, bias_p, h_pp, h_pa, root_p, NP);
    proj_author<<<(NA + 7) / 8, 256, 0, stream>>>(x_author, Wcomb_a, bias_a, h_ap, root_a, NA);

    pull_paper<<<(NP + 15) / 16, 256, 0, stream>>>(
        h_pp, h_ap, root_p, csr_pp, rs_pp, rn_pp, csr_ap, rs_ap, rn_ap,
        vv, s_pp, out, NP);
    pull_author<<<(NA + 15) / 16, 256, 0, stream>>>(
        h_pa, root_a, csr_pa, rs_pa, rn_pa, vv, s_ap, NA);

    pull2<<<((size_t)NP * 4 + 255) / 256, 256, 0, stream>>>(
        s_pp, s_ap, csr_pp, rs_pp, rn_pp, csr_ap, rs_ap, rn_ap, out, NP);
}

// Round 7
// 913.284 us; speedup vs baseline: 2.8970x; 1.0561x over previous
//
#include <hip/hip_runtime.h>

// ---------------------------------------------------------------------------
// HeteroSAGE: CSR pull; CSR build uses XCD-pinned dst-windows so each csr
// write window lives in exactly one XCD's L2 (kills partial-line writebacks).
//   hist3 -> scan -> fill_all (XCD-pinned windows) -> proj (h bf16 + root) ->
//   pull (tiny LDS, 8 waves/EU, unroll-4 gathers) -> pull2 scalar layer-2.
// ---------------------------------------------------------------------------

typedef unsigned short ushort_t;

#define WBITS 15   // 32768-dst windows: csr window ~1.8MB -> fits one XCD L2

__device__ inline ushort_t f2bf(float f) {
    unsigned u = __float_as_uint(f);
    unsigned r = (u + 0x7FFFu + ((u >> 16) & 1u)) >> 16;
    return (ushort_t)r;
}
__device__ inline float bf2f_lo(unsigned u) { return __uint_as_float(u << 16); }
__device__ inline float bf2f_hi(unsigned u) { return __uint_as_float(u & 0xFFFF0000u); }

__global__ void prep_weights(
    const float* __restrict__ Wl1_pp, const float* __restrict__ Wr1_pp,
    const float* __restrict__ Wl1_ap, const float* __restrict__ Wr1_ap,
    const float* __restrict__ Wl1_pa, const float* __restrict__ Wr1_pa,
    const float* __restrict__ bl1_pp, const float* __restrict__ bl1_ap,
    const float* __restrict__ bl1_pa,
    const float* __restrict__ Wl2_pp, const float* __restrict__ bl2_pp,
    const float* __restrict__ Wr2_pp,
    const float* __restrict__ Wl2_ap, const float* __restrict__ bl2_ap,
    const float* __restrict__ Wr2_ap,
    const float* __restrict__ W_lin, const float* __restrict__ b_lin,
    float* __restrict__ Wcomb_p,  // 64 x 96: [Wl1_pp | Wl1_pa | Wr1_pp+Wr1_ap]
    float* __restrict__ Wcomb_a,  // 64 x 64: [Wl1_ap | Wr1_pa]
    float* __restrict__ bias_p,   // 32
    float* __restrict__ bias_a,   // 32
    float* __restrict__ vv)       // [0:32) v_pp  [32:64) v_r  [64] c2  [96:128) v_ap
{
    int t = threadIdx.x;
    for (int idx = t; idx < 64 * 96; idx += 256) {
        int i = idx / 96, j = idx % 96;
        float v;
        if (j < 32)       v = Wl1_pp[i * 32 + j];
        else if (j < 64)  v = Wl1_pa[i * 32 + (j - 32)];
        else              v = Wr1_pp[i * 32 + (j - 64)] + Wr1_ap[i * 32 + (j - 64)];
        Wcomb_p[idx] = v;
    }
    for (int idx = t; idx < 64 * 64; idx += 256) {
        int i = idx / 64, j = idx % 64;
        Wcomb_a[idx] = (j < 32) ? Wl1_ap[i * 32 + j] : Wr1_pa[i * 32 + (j - 32)];
    }
    if (t < 32) {
        bias_p[t] = bl1_pp[t] + bl1_ap[t];
        bias_a[t] = bl1_pa[t];
        float vpp = 0.f, vr = 0.f, vap = 0.f;
        for (int j = 0; j < 32; ++j) {
            float wl = W_lin[j];
            vpp += Wl2_pp[t * 32 + j] * wl;
            vr  += (Wr2_pp[t * 32 + j] + Wr2_ap[t * 32 + j]) * wl;
            vap += Wl2_ap[t * 32 + j] * wl;
        }
        vv[t] = vpp; vv[32 + t] = vr; vv[96 + t] = vap;
    }
    if (t == 0) {
        float c = b_lin[0];
        for (int j = 0; j < 32; ++j) c += (bl2_pp[j] + bl2_ap[j]) * W_lin[j];
        vv[64] = c;
    }
}

// fused 3-relation histogram
__global__ void hist3(const int* __restrict__ d0, int E0, int* __restrict__ c0,
                      const int* __restrict__ d1, int E1, int* __restrict__ c1,
                      const int* __restrict__ d2, int E2, int* __restrict__ c2)
{
    int t = blockIdx.x * blockDim.x + threadIdx.x;
    if (t < E0) atomicAdd(&c0[d0[t]], 1);
    else if (t < E0 + E1) atomicAdd(&c1[d1[t - E0]], 1);
    else if (t < E0 + E1 + E2) atomicAdd(&c2[d2[t - E0 - E1]], 1);
}

// chunked exclusive scan; writes row-start rs[] and working-cursor rn[] (= rs).
__global__ void scan_k(const int* __restrict__ cnt, int* __restrict__ rs,
                       int* __restrict__ rn, int* __restrict__ total, int N)
{
    __shared__ int wsum[4];
    __shared__ int bbase;
    int base = blockIdx.x * 2048 + threadIdx.x * 8;
    int v[8]; int ts = 0;
#pragma unroll
    for (int k = 0; k < 8; ++k) {
        int idx = base + k;
        v[k] = (idx < N) ? cnt[idx] : 0;
        ts += v[k];
    }
    int lane = threadIdx.x & 63;
    int incl = ts;
#pragma unroll
    for (int off = 1; off < 64; off <<= 1) {
        int o = __shfl_up(incl, off);
        if (lane >= off) incl += o;
    }
    int wid = threadIdx.x >> 6;
    if (lane == 63) wsum[wid] = incl;
    __syncthreads();
    int btot = wsum[0] + wsum[1] + wsum[2] + wsum[3];
    if (threadIdx.x == 0) bbase = atomicAdd(total, btot);
    int woff = 0;
    for (int w = 0; w < 4; ++w) if (w < wid) woff += wsum[w];
    __syncthreads();
    int run = bbase + woff + (incl - ts);
#pragma unroll
    for (int k = 0; k < 8; ++k) {
        int idx = base + k;
        if (idx < N) { rs[idx] = run; rn[idx] = run; }
        run += v[k];
    }
}

// XCD-pinned windowed fill, all 3 relations in one launch.
// window w (global id over pp|ap|pa) is processed only by blocks with
// blockIdx&7 == w&7  (blocks round-robin across XCDs), so each csr window
// is written through exactly one XCD's L2 -> full line accumulation.
__global__ void fill_all(
    const int* __restrict__ src0, const int* __restrict__ dst0,
    int* __restrict__ rn0, int* __restrict__ csr0, int E0, int np0,
    const int* __restrict__ src1, const int* __restrict__ dst1,
    int* __restrict__ rn1, int* __restrict__ csr1, int E1, int np1,
    const int* __restrict__ src2, const int* __restrict__ dst2,
    int* __restrict__ rn2, int* __restrict__ csr2, int E2, int np2)
{
    int xcd = blockIdx.x & 7;
    int bgrp = blockIdx.x >> 3;
    int nb = gridDim.x >> 3;
    int nwin = np0 + np1 + np2;
    for (int w = xcd; w < nwin; w += 8) {
        const int* src; const int* dst; int* rn; int* csr; int E; int pass;
        if (w < np0)            { src = src0; dst = dst0; rn = rn0; csr = csr0; E = E0; pass = w; }
        else if (w < np0 + np1) { src = src1; dst = dst1; rn = rn1; csr = csr1; E = E1; pass = w - np0; }
        else                    { src = src2; dst = dst2; rn = rn2; csr = csr2; E = E2; pass = w - np0 - np1; }
        for (int e = bgrp * blockDim.x + threadIdx.x; e < E; e += nb * blockDim.x) {
            int d = dst[e];
            if ((d >> WBITS) == pass) {
                int pos = atomicAdd(&rn[d], 1);
                csr[pos] = src[e];
            }
        }
    }
}

// paper projection: h_pp, h_pa (bf16 neighbor features) + root_p (f32, incl bias)
__global__ void proj_paper(const float* __restrict__ x, const float* __restrict__ Wc,
                           const float* __restrict__ bias,
                           ushort_t* __restrict__ h_pp, ushort_t* __restrict__ h_pa,
                           float* __restrict__ root_p, int N)
{
    __shared__ float Wlds[64 * 96];
    __shared__ float blds[32];
    for (int i = threadIdx.x; i < 64 * 96; i += 256) Wlds[i] = Wc[i];
    if (threadIdx.x < 32) blds[threadIdx.x] = bias[threadIdx.x];
    __syncthreads();
    int n = blockIdx.x * 8 + (threadIdx.x >> 5);
    int c = threadIdx.x & 31;
    if (n < N) {
        const float* xr = x + (size_t)n * 64;
        float a0 = 0.f, a1 = 0.f, a2 = 0.f;
#pragma unroll
        for (int i = 0; i < 64; ++i) {
            float xv = xr[i];
            a0 += xv * Wlds[i * 96 + c];
            a1 += xv * Wlds[i * 96 + 32 + c];
            a2 += xv * Wlds[i * 96 + 64 + c];
        }
        h_pp[(size_t)n * 32 + c] = f2bf(a0);
        h_pa[(size_t)n * 32 + c] = f2bf(a1);
        root_p[(size_t)n * 32 + c] = a2 + blds[c];
    }
}

__global__ void proj_author(const float* __restrict__ x, const float* __restrict__ Wc,
                            const float* __restrict__ bias,
                            ushort_t* __restrict__ h_ap, float* __restrict__ root_a, int N)
{
    __shared__ float Wlds[64 * 64];
    __shared__ float blds[32];
    for (int i = threadIdx.x; i < 64 * 64; i += 256) Wlds[i] = Wc[i];
    if (threadIdx.x < 32) blds[threadIdx.x] = bias[threadIdx.x];
    __syncthreads();
    int n = blockIdx.x * 8 + (threadIdx.x >> 5);
    int c = threadIdx.x & 31;
    if (n < N) {
        const float* xr = x + (size_t)n * 64;
        float a0 = 0.f, a1 = 0.f;
#pragma unroll
        for (int i = 0; i < 64; ++i) {
            float xv = xr[i];
            a0 += xv * Wlds[i * 64 + c];
            a1 += xv * Wlds[i * 64 + 32 + c];
        }
        h_ap[(size_t)n * 32 + c] = f2bf(a0);
        root_a[(size_t)n * 32 + c] = a1 + blds[c];
    }
}

// 16 lanes/node, 2 cols/lane, tiny LDS, high occupancy. Unroll-4 independent
// gathers; fuses mean + root + relu + layer-2 dot products.
__global__ __launch_bounds__(256, 8)
void pull_paper(const ushort_t* __restrict__ h_pp, const ushort_t* __restrict__ h_ap,
                const float* __restrict__ root,
                const int* __restrict__ csr_pp, const int* __restrict__ rs_pp,
                const int* __restrict__ rn_pp,
                const int* __restrict__ csr_ap, const int* __restrict__ rs_ap,
                const int* __restrict__ rn_ap,
                const float* __restrict__ vv,
                float* __restrict__ s_pp, float* __restrict__ out, int N)
{
    __shared__ float v0[32], v1[32];
    __shared__ float c2s;
    if (threadIdx.x < 32) { v0[threadIdx.x] = vv[threadIdx.x]; v1[threadIdx.x] = vv[32 + threadIdx.x]; }
    if (threadIdx.x == 0) c2s = vv[64];
    __syncthreads();
    int n = blockIdx.x * 16 + (threadIdx.x >> 4);
    if (n >= N) return;
    int c = threadIdx.x & 15;
    const ushort_t* hpp_c = h_pp + 2 * c;
    const ushort_t* hap_c = h_ap + 2 * c;
    // pp row
    int s1 = rs_pp[n], e1 = rn_pp[n];
    float a0 = 0.f, a1 = 0.f;
    int j = s1;
    for (; j + 4 <= e1; j += 4) {
        int i0 = csr_pp[j], i1 = csr_pp[j + 1], i2 = csr_pp[j + 2], i3 = csr_pp[j + 3];
        unsigned u0 = *(const unsigned*)(hpp_c + (size_t)i0 * 32);
        unsigned u1 = *(const unsigned*)(hpp_c + (size_t)i1 * 32);
        unsigned u2 = *(const unsigned*)(hpp_c + (size_t)i2 * 32);
        unsigned u3 = *(const unsigned*)(hpp_c + (size_t)i3 * 32);
        a0 += (bf2f_lo(u0) + bf2f_lo(u1)) + (bf2f_lo(u2) + bf2f_lo(u3));
        a1 += (bf2f_hi(u0) + bf2f_hi(u1)) + (bf2f_hi(u2) + bf2f_hi(u3));
    }
    for (; j < e1; ++j) {
        unsigned u0 = *(const unsigned*)(hpp_c + (size_t)csr_pp[j] * 32);
        a0 += bf2f_lo(u0); a1 += bf2f_hi(u0);
    }
    // ap row
    int s2 = rs_ap[n], e2 = rn_ap[n];
    float b0 = 0.f, b1 = 0.f;
    j = s2;
    for (; j + 4 <= e2; j += 4) {
        int i0 = csr_ap[j], i1 = csr_ap[j + 1], i2 = csr_ap[j + 2], i3 = csr_ap[j + 3];
        unsigned u0 = *(const unsigned*)(hap_c + (size_t)i0 * 32);
        unsigned u1 = *(const unsigned*)(hap_c + (size_t)i1 * 32);
        unsigned u2 = *(const unsigned*)(hap_c + (size_t)i2 * 32);
        unsigned u3 = *(const unsigned*)(hap_c + (size_t)i3 * 32);
        b0 += (bf2f_lo(u0) + bf2f_lo(u1)) + (bf2f_lo(u2) + bf2f_lo(u3));
        b1 += (bf2f_hi(u0) + bf2f_hi(u1)) + (bf2f_hi(u2) + bf2f_hi(u3));
    }
    for (; j < e2; ++j) {
        unsigned u0 = *(const unsigned*)(hap_c + (size_t)csr_ap[j] * 32);
        b0 += bf2f_lo(u0); b1 += bf2f_hi(u0);
    }
    float ipp = 1.0f / fmaxf((float)(e1 - s1), 1.0f);
    float iap = 1.0f / fmaxf((float)(e2 - s2), 1.0f);
    float p0 = fmaxf(root[(size_t)n * 32 + 2 * c]     + a0 * ipp + b0 * iap, 0.f);
    float p1 = fmaxf(root[(size_t)n * 32 + 2 * c + 1] + a1 * ipp + b1 * iap, 0.f);
    float d0 = p0 * v0[2 * c] + p1 * v0[2 * c + 1];
    float d1 = p0 * v1[2 * c] + p1 * v1[2 * c + 1];
#pragma unroll
    for (int off = 1; off < 16; off <<= 1) {
        d0 += __shfl_xor(d0, off);
        d1 += __shfl_xor(d1, off);
    }
    if (c == 0) { s_pp[n] = d0; out[n] = d1 + c2s; }
}

__global__ __launch_bounds__(256, 8)
void pull_author(const ushort_t* __restrict__ h_pa, const float* __restrict__ root,
                 const int* __restrict__ csr_pa, const int* __restrict__ rs_pa,
                 const int* __restrict__ rn_pa,
                 const float* __restrict__ vv, float* __restrict__ s_ap, int N)
{
    __shared__ float v0[32];
    if (threadIdx.x < 32) v0[threadIdx.x] = vv[96 + threadIdx.x];
    __syncthreads();
    int n = blockIdx.x * 16 + (threadIdx.x >> 4);
    if (n >= N) return;
    int c = threadIdx.x & 15;
    const ushort_t* hpa_c = h_pa + 2 * c;
    int s1 = rs_pa[n], e1 = rn_pa[n];
    float a0 = 0.f, a1 = 0.f;
    int j = s1;
    for (; j + 4 <= e1; j += 4) {
        int i0 = csr_pa[j], i1 = csr_pa[j + 1], i2 = csr_pa[j + 2], i3 = csr_pa[j + 3];
        unsigned u0 = *(const unsigned*)(hpa_c + (size_t)i0 * 32);
        unsigned u1 = *(const unsigned*)(hpa_c + (size_t)i1 * 32);
        unsigned u2 = *(const unsigned*)(hpa_c + (size_t)i2 * 32);
        unsigned u3 = *(const unsigned*)(hpa_c + (size_t)i3 * 32);
        a0 += (bf2f_lo(u0) + bf2f_lo(u1)) + (bf2f_lo(u2) + bf2f_lo(u3));
        a1 += (bf2f_hi(u0) + bf2f_hi(u1)) + (bf2f_hi(u2) + bf2f_hi(u3));
    }
    for (; j < e1; ++j) {
        unsigned u0 = *(const unsigned*)(hpa_c + (size_t)csr_pa[j] * 32);
        a0 += bf2f_lo(u0); a1 += bf2f_hi(u0);
    }
    float ip = 1.0f / fmaxf((float)(e1 - s1), 1.0f);
    float p0 = fmaxf(root[(size_t)n * 32 + 2 * c]     + a0 * ip, 0.f);
    float p1 = fmaxf(root[(size_t)n * 32 + 2 * c + 1] + a1 * ip, 0.f);
    float d0 = p0 * v0[2 * c] + p1 * v0[2 * c + 1];
#pragma unroll
    for (int off = 1; off < 16; off <<= 1) d0 += __shfl_xor(d0, off);
    if (c == 0) s_ap[n] = d0;
}

// layer-2 scalar pull, 4 lanes/node; s tables are small (0.8/0.4 MB).
__global__ __launch_bounds__(256, 8)
void pull2(const float* __restrict__ s_pp, const float* __restrict__ s_ap,
           const int* __restrict__ csr_pp, const int* __restrict__ rs_pp,
           const int* __restrict__ rn_pp,
           const int* __restrict__ csr_ap, const int* __restrict__ rs_ap,
           const int* __restrict__ rn_ap,
           float* __restrict__ out, int N)
{
    int g = (blockIdx.x * blockDim.x + threadIdx.x) >> 2;
    int c = threadIdx.x & 3;
    if (g >= N) return;
    int s1 = rs_pp[g], e1 = rn_pp[g];
    float t = 0.f;
    for (int j = s1 + c; j < e1; j += 4) t += s_pp[csr_pp[j]];
    int s2 = rs_ap[g], e2 = rn_ap[g];
    float u = 0.f;
    for (int j = s2 + c; j < e2; j += 4) u += s_ap[csr_ap[j]];
    t += __shfl_xor(t, 1); t += __shfl_xor(t, 2);
    u += __shfl_xor(u, 1); u += __shfl_xor(u, 2);
    if (c == 0) {
        out[g] += t / fmaxf((float)(e1 - s1), 1.f) + u / fmaxf((float)(e2 - s2), 1.f);
    }
}

extern "C" void kernel_launch(void* const* d_in, const int* in_sizes, int n_in,
                              void* d_out, int out_size, void* d_ws, size_t ws_size,
                              hipStream_t stream)
{
    const float* x_paper  = (const float*)d_in[0];
    const float* x_author = (const float*)d_in[1];
    const int* src_pp = (const int*)d_in[2];
    const int* dst_pp = (const int*)d_in[3];
    const int* src_ap = (const int*)d_in[4];
    const int* dst_ap = (const int*)d_in[5];
    const int* src_pa = (const int*)d_in[6];
    const int* dst_pa = (const int*)d_in[7];
    const float* Wl1_pp = (const float*)d_in[8];
    const float* bl1_pp = (const float*)d_in[9];
    const float* Wr1_pp = (const float*)d_in[10];
    const float* Wl1_ap = (const float*)d_in[11];
    const float* bl1_ap = (const float*)d_in[12];
    const float* Wr1_ap = (const float*)d_in[13];
    const float* Wl1_pa = (const float*)d_in[14];
    const float* bl1_pa = (const float*)d_in[15];
    const float* Wr1_pa = (const float*)d_in[16];
    const float* Wl2_pp = (const float*)d_in[17];
    const float* bl2_pp = (const float*)d_in[18];
    const float* Wr2_pp = (const float*)d_in[19];
    const float* Wl2_ap = (const float*)d_in[20];
    const float* bl2_ap = (const float*)d_in[21];
    const float* Wr2_ap = (const float*)d_in[22];
    const float* W_lin  = (const float*)d_in[23];
    const float* b_lin  = (const float*)d_in[24];

    const int NP = in_sizes[0] / 64;
    const int NA = in_sizes[1] / 64;
    const int E_PP = in_sizes[2];
    const int E_AP = in_sizes[4];
    const int E_PA = in_sizes[6];

    // ---- workspace ----
    char* wp = (char*)d_ws;
    int* cnt_pp = (int*)wp;         wp += (size_t)NP * 4;
    int* cnt_ap = (int*)wp;         wp += (size_t)NP * 4;
    int* cnt_pa = (int*)wp;         wp += (size_t)NA * 4;
    int* totals = (int*)wp;         wp += 4 * 4;
    int* rs_pp  = (int*)wp;         wp += (size_t)NP * 4;
    int* rs_ap  = (int*)wp;         wp += (size_t)NP * 4;
    int* rs_pa  = (int*)wp;         wp += (size_t)NA * 4;
    int* rn_pp  = (int*)wp;         wp += (size_t)NP * 4;
    int* rn_ap  = (int*)wp;         wp += (size_t)NP * 4;
    int* rn_pa  = (int*)wp;         wp += (size_t)NA * 4;
    int* csr_pp = (int*)wp;         wp += (size_t)E_PP * 4;
    int* csr_ap = (int*)wp;         wp += (size_t)E_AP * 4;
    int* csr_pa = (int*)wp;         wp += (size_t)E_PA * 4;
    ushort_t* h_pp = (ushort_t*)wp; wp += (size_t)NP * 32 * 2;
    ushort_t* h_pa = (ushort_t*)wp; wp += (size_t)NP * 32 * 2;
    ushort_t* h_ap = (ushort_t*)wp; wp += (size_t)NA * 32 * 2;
    float* root_p = (float*)wp;     wp += (size_t)NP * 32 * 4;
    float* root_a = (float*)wp;     wp += (size_t)NA * 32 * 4;
    float* s_pp   = (float*)wp;     wp += (size_t)NP * 4;
    float* s_ap   = (float*)wp;     wp += (size_t)NA * 4;
    float* Wcomb_p = (float*)wp;    wp += 64 * 96 * 4;
    float* Wcomb_a = (float*)wp;    wp += 64 * 64 * 4;
    float* bias_p = (float*)wp;     wp += 32 * 4;
    float* bias_a = (float*)wp;     wp += 32 * 4;
    float* vv     = (float*)wp;     wp += 128 * 4;

    float* out = (float*)d_out;

    const int np_pass = (NP + (1 << WBITS) - 1) >> WBITS;   // 7
    const int na_pass = (NA + (1 << WBITS) - 1) >> WBITS;   // 4

    // zero counts + totals (contiguous at ws start)
    hipMemsetAsync(d_ws, 0, ((size_t)(2 * NP + NA) + 4) * sizeof(int), stream);

    prep_weights<<<1, 256, 0, stream>>>(
        Wl1_pp, Wr1_pp, Wl1_ap, Wr1_ap, Wl1_pa, Wr1_pa,
        bl1_pp, bl1_ap, bl1_pa,
        Wl2_pp, bl2_pp, Wr2_pp, Wl2_ap, bl2_ap, Wr2_ap,
        W_lin, b_lin, Wcomb_p, Wcomb_a, bias_p, bias_a, vv);

    int Etot = E_PP + E_AP + E_PA;
    hist3<<<(Etot + 255) / 256, 256, 0, stream>>>(
        dst_pp, E_PP, cnt_pp, dst_ap, E_AP, cnt_ap, dst_pa, E_PA, cnt_pa);

    scan_k<<<(NP + 2047) / 2048, 256, 0, stream>>>(cnt_pp, rs_pp, rn_pp, totals + 0, NP);
    scan_k<<<(NP + 2047) / 2048, 256, 0, stream>>>(cnt_ap, rs_ap, rn_ap, totals + 1, NP);
    scan_k<<<(NA + 2047) / 2048, 256, 0, stream>>>(cnt_pa, rs_pa, rn_pa, totals + 2, NA);

    fill_all<<<2048, 256, 0, stream>>>(
        src_pp, dst_pp, rn_pp, csr_pp, E_PP, np_pass,
        src_ap, dst_ap, rn_ap, csr_ap, E_AP, np_pass,
        src_pa, dst_pa, rn_pa, csr_pa, E_PA, na_pass);

    proj_paper<<<(NP + 7) / 8, 256, 0, stream>>>(x_paper, Wcomb_p, bias_p, h_pp, h_pa, root_p, NP);
    proj_author<<<(NA + 7) / 8, 256, 0, stream>>>(x_author, Wcomb_a, bias_a, h_ap, root_a, NA);

    pull_paper<<<(NP + 15) / 16, 256, 0, stream>>>(
        h_pp, h_ap, root_p, csr_pp, rs_pp, rn_pp, csr_ap, rs_ap, rn_ap,
        vv, s_pp, out, NP);
    pull_author<<<(NA + 15) / 16, 256, 0, stream>>>(
        h_pa, root_a, csr_pa, rs_pa, rn_pa, vv, s_ap, NA);

    pull2<<<((size_t)NP * 4 + 255) / 256, 256, 0, stream>>>(
        s_pp, s_ap, csr_pp, rs_pp, rn_pp, csr_ap, rs_ap, rn_ap, out, NP);
}

// Round 8
// 878.220 us; speedup vs baseline: 3.0127x; 1.0399x over previous
//
#include <hip/hip_runtime.h>

// ---------------------------------------------------------------------------
// HeteroSAGE: CSR pull. Build: hist3 computes counts AND per-edge ranks
// (atomicAdd return value), so the fill is atomic-free stores at
// csr[rs[d]+rank[e]]. Fill keeps dst-windows + XCD pinning + nontemporal
// streams so csr lines accumulate fully in one XCD's L2.
//   hist3(+rank) -> scan(rs) -> fill_all -> proj (h bf16 + root f32) ->
//   pull (tiny LDS, 8 waves/EU, unroll-4 gathers) -> pull2 scalar layer-2.
// ---------------------------------------------------------------------------

typedef unsigned short ushort_t;

#define WBITS 15   // 32768-dst windows: csr window ~2MB, owned by one XCD L2

__device__ inline ushort_t f2bf(float f) {
    unsigned u = __float_as_uint(f);
    unsigned r = (u + 0x7FFFu + ((u >> 16) & 1u)) >> 16;
    return (ushort_t)r;
}
__device__ inline float bf2f_lo(unsigned u) { return __uint_as_float(u << 16); }
__device__ inline float bf2f_hi(unsigned u) { return __uint_as_float(u & 0xFFFF0000u); }
__device__ inline int ntl(const int* p) { return __builtin_nontemporal_load(p); }
__device__ inline ushort_t ntl_us(const ushort_t* p) { return __builtin_nontemporal_load(p); }

__global__ void prep_weights(
    const float* __restrict__ Wl1_pp, const float* __restrict__ Wr1_pp,
    const float* __restrict__ Wl1_ap, const float* __restrict__ Wr1_ap,
    const float* __restrict__ Wl1_pa, const float* __restrict__ Wr1_pa,
    const float* __restrict__ bl1_pp, const float* __restrict__ bl1_ap,
    const float* __restrict__ bl1_pa,
    const float* __restrict__ Wl2_pp, const float* __restrict__ bl2_pp,
    const float* __restrict__ Wr2_pp,
    const float* __restrict__ Wl2_ap, const float* __restrict__ bl2_ap,
    const float* __restrict__ Wr2_ap,
    const float* __restrict__ W_lin, const float* __restrict__ b_lin,
    float* __restrict__ Wcomb_p,  // 64 x 96: [Wl1_pp | Wl1_pa | Wr1_pp+Wr1_ap]
    float* __restrict__ Wcomb_a,  // 64 x 64: [Wl1_ap | Wr1_pa]
    float* __restrict__ bias_p,   // 32
    float* __restrict__ bias_a,   // 32
    float* __restrict__ vv)       // [0:32) v_pp  [32:64) v_r  [64] c2  [96:128) v_ap
{
    int t = threadIdx.x;
    for (int idx = t; idx < 64 * 96; idx += 256) {
        int i = idx / 96, j = idx % 96;
        float v;
        if (j < 32)       v = Wl1_pp[i * 32 + j];
        else if (j < 64)  v = Wl1_pa[i * 32 + (j - 32)];
        else              v = Wr1_pp[i * 32 + (j - 64)] + Wr1_ap[i * 32 + (j - 64)];
        Wcomb_p[idx] = v;
    }
    for (int idx = t; idx < 64 * 64; idx += 256) {
        int i = idx / 64, j = idx % 64;
        Wcomb_a[idx] = (j < 32) ? Wl1_ap[i * 32 + j] : Wr1_pa[i * 32 + (j - 32)];
    }
    if (t < 32) {
        bias_p[t] = bl1_pp[t] + bl1_ap[t];
        bias_a[t] = bl1_pa[t];
        float vpp = 0.f, vr = 0.f, vap = 0.f;
        for (int j = 0; j < 32; ++j) {
            float wl = W_lin[j];
            vpp += Wl2_pp[t * 32 + j] * wl;
            vr  += (Wr2_pp[t * 32 + j] + Wr2_ap[t * 32 + j]) * wl;
            vap += Wl2_ap[t * 32 + j] * wl;
        }
        vv[t] = vpp; vv[32 + t] = vr; vv[96 + t] = vap;
    }
    if (t == 0) {
        float c = b_lin[0];
        for (int j = 0; j < 32; ++j) c += (bl2_pp[j] + bl2_ap[j]) * W_lin[j];
        vv[64] = c;
    }
}

// fused histogram + per-edge rank (the atomicAdd old-value IS the rank)
__global__ void hist3(const int* __restrict__ d0, int E0, int* __restrict__ c0, ushort_t* __restrict__ r0,
                      const int* __restrict__ d1, int E1, int* __restrict__ c1, ushort_t* __restrict__ r1,
                      const int* __restrict__ d2, int E2, int* __restrict__ c2, ushort_t* __restrict__ r2)
{
    int t = blockIdx.x * blockDim.x + threadIdx.x;
    if (t < E0) {
        r0[t] = (ushort_t)atomicAdd(&c0[ntl(d0 + t)], 1);
    } else if (t < E0 + E1) {
        int e = t - E0;
        r1[e] = (ushort_t)atomicAdd(&c1[ntl(d1 + e)], 1);
    } else if (t < E0 + E1 + E2) {
        int e = t - E0 - E1;
        r2[e] = (ushort_t)atomicAdd(&c2[ntl(d2 + e)], 1);
    }
}

// chunked exclusive scan; writes row-start rs[].
__global__ void scan_k(const int* __restrict__ cnt, int* __restrict__ rs,
                       int* __restrict__ total, int N)
{
    __shared__ int wsum[4];
    __shared__ int bbase;
    int base = blockIdx.x * 2048 + threadIdx.x * 8;
    int v[8]; int ts = 0;
#pragma unroll
    for (int k = 0; k < 8; ++k) {
        int idx = base + k;
        v[k] = (idx < N) ? cnt[idx] : 0;
        ts += v[k];
    }
    int lane = threadIdx.x & 63;
    int incl = ts;
#pragma unroll
    for (int off = 1; off < 64; off <<= 1) {
        int o = __shfl_up(incl, off);
        if (lane >= off) incl += o;
    }
    int wid = threadIdx.x >> 6;
    if (lane == 63) wsum[wid] = incl;
    __syncthreads();
    int btot = wsum[0] + wsum[1] + wsum[2] + wsum[3];
    if (threadIdx.x == 0) bbase = atomicAdd(total, btot);
    int woff = 0;
    for (int w = 0; w < 4; ++w) if (w < wid) woff += wsum[w];
    __syncthreads();
    int run = bbase + woff + (incl - ts);
#pragma unroll
    for (int k = 0; k < 8; ++k) {
        int idx = base + k;
        if (idx < N) rs[idx] = run;
        run += v[k];
    }
}

// Atomic-free windowed fill, all 3 relations in one launch, XCD-pinned:
// window w handled only by blocks with blockIdx&7 == w&7 so each csr window's
// dirty lines live in exactly one XCD's L2. Edge/rank streams nontemporal.
__global__ void fill_all(
    const int* __restrict__ src0, const int* __restrict__ dst0,
    const ushort_t* __restrict__ rk0, const int* __restrict__ rs0,
    int* __restrict__ csr0, int E0, int np0,
    const int* __restrict__ src1, const int* __restrict__ dst1,
    const ushort_t* __restrict__ rk1, const int* __restrict__ rs1,
    int* __restrict__ csr1, int E1, int np1,
    const int* __restrict__ src2, const int* __restrict__ dst2,
    const ushort_t* __restrict__ rk2, const int* __restrict__ rs2,
    int* __restrict__ csr2, int E2, int np2)
{
    int xcd = blockIdx.x & 7;
    int bgrp = blockIdx.x >> 3;
    int nb = gridDim.x >> 3;
    int nwin = np0 + np1 + np2;
    for (int w = xcd; w < nwin; w += 8) {
        const int* src; const int* dst; const ushort_t* rk; const int* rs;
        int* csr; int E; int pass;
        if (w < np0)            { src = src0; dst = dst0; rk = rk0; rs = rs0; csr = csr0; E = E0; pass = w; }
        else if (w < np0 + np1) { src = src1; dst = dst1; rk = rk1; rs = rs1; csr = csr1; E = E1; pass = w - np0; }
        else                    { src = src2; dst = dst2; rk = rk2; rs = rs2; csr = csr2; E = E2; pass = w - np0 - np1; }
        for (int e = bgrp * blockDim.x + threadIdx.x; e < E; e += nb * blockDim.x) {
            int d = ntl(dst + e);
            if ((d >> WBITS) == pass) {
                csr[rs[d] + (int)ntl_us(rk + e)] = ntl(src + e);
            }
        }
    }
}

// paper projection: h_pp, h_pa (bf16 neighbor features) + root_p (f32, incl bias)
__global__ void proj_paper(const float* __restrict__ x, const float* __restrict__ Wc,
                           const float* __restrict__ bias,
                           ushort_t* __restrict__ h_pp, ushort_t* __restrict__ h_pa,
                           float* __restrict__ root_p, int N)
{
    __shared__ float Wlds[64 * 96];
    __shared__ float blds[32];
    for (int i = threadIdx.x; i < 64 * 96; i += 256) Wlds[i] = Wc[i];
    if (threadIdx.x < 32) blds[threadIdx.x] = bias[threadIdx.x];
    __syncthreads();
    int n = blockIdx.x * 8 + (threadIdx.x >> 5);
    int c = threadIdx.x & 31;
    if (n < N) {
        const float* xr = x + (size_t)n * 64;
        float a0 = 0.f, a1 = 0.f, a2 = 0.f;
#pragma unroll
        for (int i = 0; i < 64; ++i) {
            float xv = xr[i];
            a0 += xv * Wlds[i * 96 + c];
            a1 += xv * Wlds[i * 96 + 32 + c];
            a2 += xv * Wlds[i * 96 + 64 + c];
        }
        h_pp[(size_t)n * 32 + c] = f2bf(a0);
        h_pa[(size_t)n * 32 + c] = f2bf(a1);
        root_p[(size_t)n * 32 + c] = a2 + blds[c];
    }
}

__global__ void proj_author(const float* __restrict__ x, const float* __restrict__ Wc,
                            const float* __restrict__ bias,
                            ushort_t* __restrict__ h_ap, float* __restrict__ root_a, int N)
{
    __shared__ float Wlds[64 * 64];
    __shared__ float blds[32];
    for (int i = threadIdx.x; i < 64 * 64; i += 256) Wlds[i] = Wc[i];
    if (threadIdx.x < 32) blds[threadIdx.x] = bias[threadIdx.x];
    __syncthreads();
    int n = blockIdx.x * 8 + (threadIdx.x >> 5);
    int c = threadIdx.x & 31;
    if (n < N) {
        const float* xr = x + (size_t)n * 64;
        float a0 = 0.f, a1 = 0.f;
#pragma unroll
        for (int i = 0; i < 64; ++i) {
            float xv = xr[i];
            a0 += xv * Wlds[i * 64 + c];
            a1 += xv * Wlds[i * 64 + 32 + c];
        }
        h_ap[(size_t)n * 32 + c] = f2bf(a0);
        root_a[(size_t)n * 32 + c] = a1 + blds[c];
    }
}

// 16 lanes/node, 2 cols/lane, tiny LDS, high occupancy. Unroll-4 independent
// gathers; fuses mean + root + relu + layer-2 dot products.
__global__ __launch_bounds__(256, 8)
void pull_paper(const ushort_t* __restrict__ h_pp, const ushort_t* __restrict__ h_ap,
                const float* __restrict__ root,
                const int* __restrict__ csr_pp, const int* __restrict__ rs_pp,
                const int* __restrict__ cnt_pp,
                const int* __restrict__ csr_ap, const int* __restrict__ rs_ap,
                const int* __restrict__ cnt_ap,
                const float* __restrict__ vv,
                float* __restrict__ s_pp, float* __restrict__ out, int N)
{
    __shared__ float v0[32], v1[32];
    __shared__ float c2s;
    if (threadIdx.x < 32) { v0[threadIdx.x] = vv[threadIdx.x]; v1[threadIdx.x] = vv[32 + threadIdx.x]; }
    if (threadIdx.x == 0) c2s = vv[64];
    __syncthreads();
    int n = blockIdx.x * 16 + (threadIdx.x >> 4);
    if (n >= N) return;
    int c = threadIdx.x & 15;
    const ushort_t* hpp_c = h_pp + 2 * c;
    const ushort_t* hap_c = h_ap + 2 * c;
    // pp row
    int s1 = rs_pp[n], k1 = cnt_pp[n], e1 = s1 + k1;
    float a0 = 0.f, a1 = 0.f;
    int j = s1;
    for (; j + 4 <= e1; j += 4) {
        int i0 = ntl(csr_pp + j), i1 = ntl(csr_pp + j + 1);
        int i2 = ntl(csr_pp + j + 2), i3 = ntl(csr_pp + j + 3);
        unsigned u0 = *(const unsigned*)(hpp_c + (size_t)i0 * 32);
        unsigned u1 = *(const unsigned*)(hpp_c + (size_t)i1 * 32);
        unsigned u2 = *(const unsigned*)(hpp_c + (size_t)i2 * 32);
        unsigned u3 = *(const unsigned*)(hpp_c + (size_t)i3 * 32);
        a0 += (bf2f_lo(u0) + bf2f_lo(u1)) + (bf2f_lo(u2) + bf2f_lo(u3));
        a1 += (bf2f_hi(u0) + bf2f_hi(u1)) + (bf2f_hi(u2) + bf2f_hi(u3));
    }
    for (; j < e1; ++j) {
        unsigned u0 = *(const unsigned*)(hpp_c + (size_t)ntl(csr_pp + j) * 32);
        a0 += bf2f_lo(u0); a1 += bf2f_hi(u0);
    }
    // ap row
    int s2 = rs_ap[n], k2 = cnt_ap[n], e2 = s2 + k2;
    float b0 = 0.f, b1 = 0.f;
    j = s2;
    for (; j + 4 <= e2; j += 4) {
        int i0 = ntl(csr_ap + j), i1 = ntl(csr_ap + j + 1);
        int i2 = ntl(csr_ap + j + 2), i3 = ntl(csr_ap + j + 3);
        unsigned u0 = *(const unsigned*)(hap_c + (size_t)i0 * 32);
        unsigned u1 = *(const unsigned*)(hap_c + (size_t)i1 * 32);
        unsigned u2 = *(const unsigned*)(hap_c + (size_t)i2 * 32);
        unsigned u3 = *(const unsigned*)(hap_c + (size_t)i3 * 32);
        b0 += (bf2f_lo(u0) + bf2f_lo(u1)) + (bf2f_lo(u2) + bf2f_lo(u3));
        b1 += (bf2f_hi(u0) + bf2f_hi(u1)) + (bf2f_hi(u2) + bf2f_hi(u3));
    }
    for (; j < e2; ++j) {
        unsigned u0 = *(const unsigned*)(hap_c + (size_t)ntl(csr_ap + j) * 32);
        b0 += bf2f_lo(u0); b1 += bf2f_hi(u0);
    }
    float ipp = 1.0f / fmaxf((float)k1, 1.0f);
    float iap = 1.0f / fmaxf((float)k2, 1.0f);
    float p0 = fmaxf(root[(size_t)n * 32 + 2 * c]     + a0 * ipp + b0 * iap, 0.f);
    float p1 = fmaxf(root[(size_t)n * 32 + 2 * c + 1] + a1 * ipp + b1 * iap, 0.f);
    float d0 = p0 * v0[2 * c] + p1 * v0[2 * c + 1];
    float d1 = p0 * v1[2 * c] + p1 * v1[2 * c + 1];
#pragma unroll
    for (int off = 1; off < 16; off <<= 1) {
        d0 += __shfl_xor(d0, off);
        d1 += __shfl_xor(d1, off);
    }
    if (c == 0) { s_pp[n] = d0; out[n] = d1 + c2s; }
}

__global__ __launch_bounds__(256, 8)
void pull_author(const ushort_t* __restrict__ h_pa, const float* __restrict__ root,
                 const int* __restrict__ csr_pa, const int* __restrict__ rs_pa,
                 const int* __restrict__ cnt_pa,
                 const float* __restrict__ vv, float* __restrict__ s_ap, int N)
{
    __shared__ float v0[32];
    if (threadIdx.x < 32) v0[threadIdx.x] = vv[96 + threadIdx.x];
    __syncthreads();
    int n = blockIdx.x * 16 + (threadIdx.x >> 4);
    if (n >= N) return;
    int c = threadIdx.x & 15;
    const ushort_t* hpa_c = h_pa + 2 * c;
    int s1 = rs_pa[n], k1 = cnt_pa[n], e1 = s1 + k1;
    float a0 = 0.f, a1 = 0.f;
    int j = s1;
    for (; j + 4 <= e1; j += 4) {
        int i0 = ntl(csr_pa + j), i1 = ntl(csr_pa + j + 1);
        int i2 = ntl(csr_pa + j + 2), i3 = ntl(csr_pa + j + 3);
        unsigned u0 = *(const unsigned*)(hpa_c + (size_t)i0 * 32);
        unsigned u1 = *(const unsigned*)(hpa_c + (size_t)i1 * 32);
        unsigned u2 = *(const unsigned*)(hpa_c + (size_t)i2 * 32);
        unsigned u3 = *(const unsigned*)(hpa_c + (size_t)i3 * 32);
        a0 += (bf2f_lo(u0) + bf2f_lo(u1)) + (bf2f_lo(u2) + bf2f_lo(u3));
        a1 += (bf2f_hi(u0) + bf2f_hi(u1)) + (bf2f_hi(u2) + bf2f_hi(u3));
    }
    for (; j < e1; ++j) {
        unsigned u0 = *(const unsigned*)(hpa_c + (size_t)ntl(csr_pa + j) * 32);
        a0 += bf2f_lo(u0); a1 += bf2f_hi(u0);
    }
    float ip = 1.0f / fmaxf((float)k1, 1.0f);
    float p0 = fmaxf(root[(size_t)n * 32 + 2 * c]     + a0 * ip, 0.f);
    float p1 = fmaxf(root[(size_t)n * 32 + 2 * c + 1] + a1 * ip, 0.f);
    float d0 = p0 * v0[2 * c] + p1 * v0[2 * c + 1];
#pragma unroll
    for (int off = 1; off < 16; off <<= 1) d0 += __shfl_xor(d0, off);
    if (c == 0) s_ap[n] = d0;
}

// layer-2 scalar pull, 4 lanes/node; s tables are small (0.8/0.4 MB, L2-resident).
__global__ __launch_bounds__(256, 8)
void pull2(const float* __restrict__ s_pp, const float* __restrict__ s_ap,
           const int* __restrict__ csr_pp, const int* __restrict__ rs_pp,
           const int* __restrict__ cnt_pp,
           const int* __restrict__ csr_ap, const int* __restrict__ rs_ap,
           const int* __restrict__ cnt_ap,
           float* __restrict__ out, int N)
{
    int g = (blockIdx.x * blockDim.x + threadIdx.x) >> 2;
    int c = threadIdx.x & 3;
    if (g >= N) return;
    int s1 = rs_pp[g], k1 = cnt_pp[g], e1 = s1 + k1;
    float t = 0.f;
    for (int j = s1 + c; j < e1; j += 4) t += s_pp[ntl(csr_pp + j)];
    int s2 = rs_ap[g], k2 = cnt_ap[g], e2 = s2 + k2;
    float u = 0.f;
    for (int j = s2 + c; j < e2; j += 4) u += s_ap[ntl(csr_ap + j)];
    t += __shfl_xor(t, 1); t += __shfl_xor(t, 2);
    u += __shfl_xor(u, 1); u += __shfl_xor(u, 2);
    if (c == 0) {
        out[g] += t / fmaxf((float)k1, 1.f) + u / fmaxf((float)k2, 1.f);
    }
}

extern "C" void kernel_launch(void* const* d_in, const int* in_sizes, int n_in,
                              void* d_out, int out_size, void* d_ws, size_t ws_size,
                              hipStream_t stream)
{
    const float* x_paper  = (const float*)d_in[0];
    const float* x_author = (const float*)d_in[1];
    const int* src_pp = (const int*)d_in[2];
    const int* dst_pp = (const int*)d_in[3];
    const int* src_ap = (const int*)d_in[4];
    const int* dst_ap = (const int*)d_in[5];
    const int* src_pa = (const int*)d_in[6];
    const int* dst_pa = (const int*)d_in[7];
    const float* Wl1_pp = (const float*)d_in[8];
    const float* bl1_pp = (const float*)d_in[9];
    const float* Wr1_pp = (const float*)d_in[10];
    const float* Wl1_ap = (const float*)d_in[11];
    const float* bl1_ap = (const float*)d_in[12];
    const float* Wr1_ap = (const float*)d_in[13];
    const float* Wl1_pa = (const float*)d_in[14];
    const float* bl1_pa = (const float*)d_in[15];
    const float* Wr1_pa = (const float*)d_in[16];
    const float* Wl2_pp = (const float*)d_in[17];
    const float* bl2_pp = (const float*)d_in[18];
    const float* Wr2_pp = (const float*)d_in[19];
    const float* Wl2_ap = (const float*)d_in[20];
    const float* bl2_ap = (const float*)d_in[21];
    const float* Wr2_ap = (const float*)d_in[22];
    const float* W_lin  = (const float*)d_in[23];
    const float* b_lin  = (const float*)d_in[24];

    const int NP = in_sizes[0] / 64;
    const int NA = in_sizes[1] / 64;
    const int E_PP = in_sizes[2];
    const int E_AP = in_sizes[4];
    const int E_PA = in_sizes[6];

    // ---- workspace ----
    char* wp = (char*)d_ws;
    int* cnt_pp = (int*)wp;         wp += (size_t)NP * 4;
    int* cnt_ap = (int*)wp;         wp += (size_t)NP * 4;
    int* cnt_pa = (int*)wp;         wp += (size_t)NA * 4;
    int* totals = (int*)wp;         wp += 4 * 4;
    int* rs_pp  = (int*)wp;         wp += (size_t)NP * 4;
    int* rs_ap  = (int*)wp;         wp += (size_t)NP * 4;
    int* rs_pa  = (int*)wp;         wp += (size_t)NA * 4;
    int* csr_pp = (int*)wp;         wp += (size_t)E_PP * 4;
    int* csr_ap = (int*)wp;         wp += (size_t)E_AP * 4;
    int* csr_pa = (int*)wp;         wp += (size_t)E_PA * 4;
    ushort_t* rk_pp = (ushort_t*)wp; wp += (size_t)E_PP * 2;
    ushort_t* rk_ap = (ushort_t*)wp; wp += (size_t)E_AP * 2;
    ushort_t* rk_pa = (ushort_t*)wp; wp += (size_t)E_PA * 2;
    ushort_t* h_pp = (ushort_t*)wp; wp += (size_t)NP * 32 * 2;
    ushort_t* h_pa = (ushort_t*)wp; wp += (size_t)NP * 32 * 2;
    ushort_t* h_ap = (ushort_t*)wp; wp += (size_t)NA * 32 * 2;
    float* root_p = (float*)wp;     wp += (size_t)NP * 32 * 4;
    float* root_a = (float*)wp;     wp += (size_t)NA * 32 * 4;
    float* s_pp   = (float*)wp;     wp += (size_t)NP * 4;
    float* s_ap   = (float*)wp;     wp += (size_t)NA * 4;
    float* Wcomb_p = (float*)wp;    wp += 64 * 96 * 4;
    float* Wcomb_a = (float*)wp;    wp += 64 * 64 * 4;
    float* bias_p = (float*)wp;     wp += 32 * 4;
    float* bias_a = (float*)wp;     wp += 32 * 4;
    float* vv     = (float*)wp;     wp += 128 * 4;

    float* out = (float*)d_out;

    const int np_pass = (NP + (1 << WBITS) - 1) >> WBITS;   // 7
    const int na_pass = (NA + (1 << WBITS) - 1) >> WBITS;   // 4

    // zero counts + totals (contiguous at ws start)
    hipMemsetAsync(d_ws, 0, ((size_t)(2 * NP + NA) + 4) * sizeof(int), stream);

    prep_weights<<<1, 256, 0, stream>>>(
        Wl1_pp, Wr1_pp, Wl1_ap, Wr1_ap, Wl1_pa, Wr1_pa,
        bl1_pp, bl1_ap, bl1_pa,
        Wl2_pp, bl2_pp, Wr2_pp, Wl2_ap, bl2_ap, Wr2_ap,
        W_lin, b_lin, Wcomb_p, Wcomb_a, bias_p, bias_a, vv);

    int Etot = E_PP + E_AP + E_PA;
    hist3<<<(Etot + 255) / 256, 256, 0, stream>>>(
        dst_pp, E_PP, cnt_pp, rk_pp,
        dst_ap, E_AP, cnt_ap, rk_ap,
        dst_pa, E_PA, cnt_pa, rk_pa);

    scan_k<<<(NP + 2047) / 2048, 256, 0, stream>>>(cnt_pp, rs_pp, totals + 0, NP);
    scan_k<<<(NP + 2047) / 2048, 256, 0, stream>>>(cnt_ap, rs_ap, totals + 1, NP);
    scan_k<<<(NA + 2047) / 2048, 256, 0, stream>>>(cnt_pa, rs_pa, totals + 2, NA);

    fill_all<<<2048, 256, 0, stream>>>(
        src_pp, dst_pp, rk_pp, rs_pp, csr_pp, E_PP, np_pass,
        src_ap, dst_ap, rk_ap, rs_ap, csr_ap, E_AP, np_pass,
        src_pa, dst_pa, rk_pa, rs_pa, csr_pa, E_PA, na_pass);

    proj_paper<<<(NP + 7) / 8, 256, 0, stream>>>(x_paper, Wcomb_p, bias_p, h_pp, h_pa, root_p, NP);
    proj_author<<<(NA + 7) / 8, 256, 0, stream>>>(x_author, Wcomb_a, bias_a, h_ap, root_a, NA);

    pull_paper<<<(NP + 15) / 16, 256, 0, stream>>>(
        h_pp, h_ap, root_p, csr_pp, rs_pp, cnt_pp, csr_ap, rs_ap, cnt_ap,
        vv, s_pp, out, NP);
    pull_author<<<(NA + 15) / 16, 256, 0, stream>>>(
        h_pa, root_a, csr_pa, rs_pa, cnt_pa, vv, s_ap, NA);

    pull2<<<((size_t)NP * 4 + 255) / 256, 256, 0, stream>>>(
        s_pp, s_ap, csr_pp, rs_pp, cnt_pp, csr_ap, rs_ap, cnt_ap, out, NP);
}